// Round 13
// baseline (177.945 us; speedup 1.0000x reference)
//
#include <hip/hip_runtime.h>
#include <math.h>

#define A_N 10647
#define C_N 80
#define K_N 500
#define CONF_THRF 0.3f
#define NMS_THRF 0.5f

#define NBUCK 1024              // scores/ub in (0,1): bits>>20 < 1016
#define CAND_N 2048
#define CAND_TARGET 600         // >=600 highest-ub rows get exact scores -> t

typedef float f32x4 __attribute__((ext_vector_type(4)));

__device__ __forceinline__ float sigmoid_ref(float x) {
    float e = expf(-x);            // ocml expf, ~1ulp
    return 1.0f / (1.0f + e);      // IEEE add + IEEE div (no fast-math)
}

__device__ __forceinline__ unsigned bucket_of(float v) {
    unsigned u = __float_as_uint(v) >> 20;
    return u > 1023u ? 1023u : u;
}

__device__ __forceinline__ unsigned long long shfl_u64(unsigned long long v, int src) {
    unsigned int lo = (unsigned int)v, hi = (unsigned int)(v >> 32);
    lo = __shfl(lo, src, 64);
    hi = __shfl(hi, src, 64);
    return ((unsigned long long)hi << 32) | (unsigned long long)lo;
}

__device__ __forceinline__ unsigned long long shfl_xor_u64(unsigned long long v, int mask) {
    unsigned int lo = (unsigned int)v, hi = (unsigned int)(v >> 32);
    lo = __shfl_xor(lo, mask, 64);
    hi = __shfl_xor(hi, mask, 64);
    return ((unsigned long long)hi << 32) | (unsigned long long)lo;
}

// Exact per-row reduction over a 4-lane group (v = 5 f32x4/lane, slot sub+4j).
// Returns cls_conf (max sigmoid) + argmax label, ref-exact (see R3 notes).
__device__ __forceinline__ void reduce_core(
    const f32x4 v[5], int sub, float& sbest, int& ibest) {
    float m = -3.4e38f;
    #pragma unroll
    for (int j = 0; j < 5; ++j)
        m = fmaxf(m, fmaxf(fmaxf(v[j][0], v[j][1]), fmaxf(v[j][2], v[j][3])));
    m = fmaxf(m, __shfl_xor(m, 1, 64));
    m = fmaxf(m, __shfl_xor(m, 2, 64));

    const float win = m - 1e-4f;
    int imin = 0x7FFFFFFF, cnt = 0;
    #pragma unroll
    for (int j = 0; j < 5; ++j) {
        #pragma unroll
        for (int t = 0; t < 4; ++t) {
            int idx = (sub + 4 * j) * 4 + t;
            if (v[j][t] == m && idx < imin) imin = idx;
            cnt += (v[j][t] >= win) ? 1 : 0;
        }
    }
    {
        int o = __shfl_xor(imin, 1, 64); imin = imin < o ? imin : o;
        o = __shfl_xor(imin, 2, 64);     imin = imin < o ? imin : o;
        cnt += __shfl_xor(cnt, 1, 64);
        cnt += __shfl_xor(cnt, 2, 64);
    }

    if (cnt >= 2) {
        // rare near-tie: redo exactly as ref (max sigmoid, first occurrence)
        unsigned long long key = 0ull;
        #pragma unroll
        for (int j = 0; j < 5; ++j) {
            #pragma unroll
            for (int t = 0; t < 4; ++t) {
                float x = v[j][t];
                if (x >= win) {
                    int idx = (sub + 4 * j) * 4 + t;
                    float s = sigmoid_ref(x);
                    unsigned long long k =
                        ((unsigned long long)__float_as_uint(s) << 32) |
                        (unsigned long long)(0xFFFFu - (unsigned)idx);
                    if (k > key) key = k;
                }
            }
        }
        unsigned long long o = shfl_xor_u64(key, 1); if (o > key) key = o;
        o = shfl_xor_u64(key, 2);                    if (o > key) key = o;
        sbest = __uint_as_float((unsigned int)(key >> 32));
        ibest = 0xFFFF - (int)(key & 0xFFFFull);
    } else {
        sbest = sigmoid_ref(m);
        ibest = imin;
    }
}

// K_A: per batch. ub histogram over pconf -> u* = max bucket with suffix>=600.
// Also zeroes this batch's shist slice.
__global__ __launch_bounds__(1024) void ustar_kernel(
    const float* __restrict__ pconf,
    unsigned* __restrict__ ustar,
    unsigned* __restrict__ shist) {
    __shared__ unsigned hist[NBUCK];
    const int b = blockIdx.x, tid = threadIdx.x;
    hist[tid] = 0u;
    shist[(size_t)b * NBUCK + tid] = 0u;
    __syncthreads();
    for (int i = tid; i < A_N; i += 1024) {
        float ubv = sigmoid_ref(pconf[(size_t)b * A_N + i]);
        atomicAdd(&hist[bucket_of(ubv)], 1u);
    }
    __syncthreads();
    for (int d = 1; d < NBUCK; d <<= 1) {
        unsigned v = (tid + d < NBUCK) ? hist[tid + d] : 0u;
        __syncthreads();
        hist[tid] += v;
        __syncthreads();
    }
    if (hist[tid] >= CAND_TARGET && (tid == NBUCK - 1 || hist[tid + 1] < CAND_TARGET))
        ustar[b] = (unsigned)tid;
}

// K_B: exact scores for candidate rows (ub bucket >= u*); count into shist.
__global__ __launch_bounds__(256) void cand_kernel(
    const float* __restrict__ pconf,
    const float* __restrict__ pcls,
    float* __restrict__ scores,
    int* __restrict__ labels,
    const unsigned* __restrict__ ustar,
    unsigned* __restrict__ shist,
    int total) {
    const int sub = threadIdx.x & 3;
    const int g0 = (blockIdx.x * 256 + threadIdx.x) >> 2;
    const int gstride = (2048 * 256) >> 2;   // 131072 groups
    for (int r = g0; r < total; r += gstride) {
        unsigned b = (unsigned)r / A_N;
        float ub = sigmoid_ref(pconf[r]);
        if (bucket_of(ub) >= ustar[b]) {
            const f32x4* rp = (const f32x4*)(pcls + (size_t)r * C_N);
            f32x4 v[5];
            #pragma unroll
            for (int j = 0; j < 5; ++j) v[j] = rp[sub + 4 * j];
            float s; int ib;
            reduce_core(v, sub, s, ib);
            float sc = __fmul_rn(s, ub);     // ref: cls_conf * conf
            if (sub == 0) {
                scores[r] = sc;
                labels[r] = ib;
                atomicAdd(&shist[(size_t)b * NBUCK + bucket_of(sc)], 1u);
            }
        }
    }
}

// K_C: per batch. t = lower edge of bucket where candidate-score suffix >= 500.
// Valid lower bound on the batch's true 500th score (>=500 exact scores >= t).
__global__ __launch_bounds__(1024) void tval_kernel(
    const unsigned* __restrict__ shist,
    float* __restrict__ tval) {
    __shared__ unsigned hist[NBUCK];
    const int b = blockIdx.x, tid = threadIdx.x;
    hist[tid] = shist[(size_t)b * NBUCK + tid];
    __syncthreads();
    for (int d = 1; d < NBUCK; d <<= 1) {
        unsigned v = (tid + d < NBUCK) ? hist[tid + d] : 0u;
        __syncthreads();
        hist[tid] += v;
        __syncthreads();
    }
    if (hist[tid] >= K_N && (tid == NBUCK - 1 || hist[tid + 1] < K_N))
        tval[b] = __uint_as_float(((unsigned)tid) << 20);
}

// K_D: remaining rows. ub < t  =>  score < ub < t <= score_500: provably not
// top-500 -> write 0, never read the row's 80 cls floats. Else compute exact.
__global__ __launch_bounds__(256) void rest_kernel(
    const float* __restrict__ pconf,
    const float* __restrict__ pcls,
    float* __restrict__ scores,
    int* __restrict__ labels,
    const unsigned* __restrict__ ustar,
    const float* __restrict__ tval,
    int total) {
    const int sub = threadIdx.x & 3;
    const int g0 = (blockIdx.x * 256 + threadIdx.x) >> 2;
    const int gstride = (2048 * 256) >> 2;
    for (int r = g0; r < total; r += gstride) {
        unsigned b = (unsigned)r / A_N;
        float ub = sigmoid_ref(pconf[r]);
        unsigned u = bucket_of(ub);
        if (u >= ustar[b]) continue;                 // done in cand_kernel
        if (ub >= tval[b]) {
            const f32x4* rp = (const f32x4*)(pcls + (size_t)r * C_N);
            f32x4 v[5];
            #pragma unroll
            for (int j = 0; j < 5; ++j) v[j] = rp[sub + 4 * j];
            float s; int ib;
            reduce_core(v, sub, s, ib);
            if (sub == 0) {
                scores[r] = __fmul_rn(s, ub);
                labels[r] = ib;
            }
        } else if (sub == 0) {
            scores[r] = 0.0f;                        // below any real score
        }
    }
}

// K_E: one block per batch. Histogram select -> 2048-key bitonic sort ->
// decode top-500 -> suppression matrix -> sequential keep-scan. (Unchanged.)
__global__ __launch_bounds__(1024) void topk_nms_kernel(
    const float* __restrict__ scores,
    const int* __restrict__ labels,
    const float* __restrict__ ptxywh,
    const float* __restrict__ grid_xy,
    const float* __restrict__ anchor_wh,
    const float* __restrict__ fsize,
    float* __restrict__ out, int B) {
    extern __shared__ unsigned char smem[];
    unsigned int* hist = (unsigned int*)smem;                     // [1024]
    unsigned long long* cand = (unsigned long long*)(smem + 4096);// [2048]
    unsigned int* cntp = (unsigned int*)(smem + 20480);
    unsigned int* Tp   = (unsigned int*)(smem + 20484);
    const int b = blockIdx.x;
    const int tid = threadIdx.x;
    const float* sb = scores + (size_t)b * A_N;

    hist[tid] = 0u;
    cand[tid] = 0ull;
    cand[tid + 1024] = 0ull;
    if (tid == 0) *cntp = 0u;
    __syncthreads();

    for (int i = tid; i < A_N; i += 1024) {
        unsigned int u = __float_as_uint(sb[i]) >> 20;
        atomicAdd(&hist[u], 1u);
    }
    __syncthreads();

    for (int d = 1; d < NBUCK; d <<= 1) {
        unsigned int v = (tid + d < NBUCK) ? hist[tid + d] : 0u;
        __syncthreads();
        hist[tid] += v;
        __syncthreads();
    }
    if (hist[tid] >= K_N && (tid == NBUCK - 1 || hist[tid + 1] < K_N)) *Tp = (unsigned)tid;
    __syncthreads();
    const unsigned int T = *Tp;
    __syncthreads();

    for (int i = tid; i < A_N; i += 1024) {
        unsigned int u = __float_as_uint(sb[i]);
        if ((u >> 20) >= T) {
            unsigned int slot = atomicAdd(cntp, 1u);
            if (slot < CAND_N)
                cand[slot] = ((unsigned long long)u << 32) |
                             (unsigned long long)(0xFFFFu - (unsigned)i);
        }
    }
    __syncthreads();

    for (int sz = 2; sz <= CAND_N; sz <<= 1) {
        for (int j = sz >> 1; j > 0; j >>= 1) {
            int i = ((tid & ~(j - 1)) << 1) | (tid & (j - 1));
            int l = i | j;
            unsigned long long a = cand[i];
            unsigned long long c = cand[l];
            bool descBlk = ((i & sz) == 0);
            if (descBlk ? (a < c) : (a > c)) { cand[i] = c; cand[l] = a; }
            __syncthreads();
        }
    }

    unsigned long long myk = 0ull;
    if (tid < K_N) myk = cand[tid];
    __syncthreads();

    float* bxL   = (float*)smem;                               // [500*4]
    float* areaL = (float*)(smem + 8000);                      // [500]
    int*   labL  = (int*)  (smem + 10000);                     // [500]
    float* valsL = (float*)(smem + 12000);                     // [500]
    unsigned long long* nzL   = (unsigned long long*)(smem + 14016); // [8]
    unsigned long long* keepL = (unsigned long long*)(smem + 14080); // [8]
    unsigned long long* supL  = (unsigned long long*)(smem + 14336); // [500*8]

    if (tid >= 512 && tid < 520) nzL[tid - 512] = 0ull;

    const size_t BK = (size_t)B * K_N;
    if (tid < K_N) {
        float scv = __uint_as_float((unsigned int)(myk >> 32));
        int idx = 0xFFFF - (int)(myk & 0xFFFFull);
        int lb = labels[(size_t)b * A_N + idx] + 1;
        const float* t4 = ptxywh + ((size_t)b * A_N + idx) * 4;
        float tx = t4[0], ty = t4[1], tw = t4[2], th = t4[3];
        float gx = grid_xy[idx * 2 + 0], gy = grid_xy[idx * 2 + 1];
        float aw = anchor_wh[idx * 2 + 0], ah = anchor_wh[idx * 2 + 1];
        float fs = fsize[idx];
        float cx = __fdiv_rn(__fadd_rn(sigmoid_ref(tx), gx), fs);
        float cy = __fdiv_rn(__fadd_rn(sigmoid_ref(ty), gy), fs);
        float wx = __fmul_rn(expf(tw), aw);
        float wy = __fmul_rn(expf(th), ah);
        float hx = __fmul_rn(0.5f, wx);
        float hy = __fmul_rn(0.5f, wy);
        float x0 = __fsub_rn(cx, hx), y0 = __fsub_rn(cy, hy);
        float x1 = __fadd_rn(cx, hx), y1 = __fadd_rn(cy, hy);
        x0 = fminf(fmaxf(x0, 0.0f), 1.0f);
        y0 = fminf(fmaxf(y0, 0.0f), 1.0f);
        x1 = fminf(fmaxf(x1, 0.0f), 1.0f);
        y1 = fminf(fmaxf(y1, 0.0f), 1.0f);
        float area = __fmul_rn(fmaxf(__fsub_rn(x1, x0), 0.0f),
                               fmaxf(__fsub_rn(y1, y0), 0.0f));
        bxL[tid * 4 + 0] = x0; bxL[tid * 4 + 1] = y0;
        bxL[tid * 4 + 2] = x1; bxL[tid * 4 + 3] = y1;
        areaL[tid] = area; labL[tid] = lb; valsL[tid] = scv;

        out[(size_t)b * K_N + tid] = (float)b;                         // ids_batch
        float* ob = out + BK + ((size_t)b * K_N + tid) * 4;            // boxes
        ob[0] = x0; ob[1] = y0; ob[2] = x1; ob[3] = y1;
        out[5 * BK + (size_t)b * K_N + tid] = (float)lb;               // labels
        out[6 * BK + (size_t)b * K_N + tid] = scv;                     // vals
    }
    __syncthreads();

    for (int task = tid; task < K_N * 8; task += 1024) {
        int i = task >> 3;
        int w = task & 7;
        float li = bxL[i * 4 + 0], ti = bxL[i * 4 + 1];
        float ri = bxL[i * 4 + 2], bi = bxL[i * 4 + 3];
        float ai = areaL[i];
        int lbi = labL[i];
        unsigned long long bits = 0ull;
        int j0 = w * 64;
        int jend = j0 + 64; if (jend > K_N) jend = K_N;
        int jst = j0 > i + 1 ? j0 : i + 1;
        for (int j = jst; j < jend; ++j) {
            if (labL[j] == lbi) {
                float lj = bxL[j * 4 + 0], tj = bxL[j * 4 + 1];
                float rj = bxL[j * 4 + 2], bj = bxL[j * 4 + 3];
                float ltx = fmaxf(li, lj), lty = fmaxf(ti, tj);
                float rbx = fminf(ri, rj), rby = fminf(bi, bj);
                float iw = fmaxf(__fsub_rn(rbx, ltx), 0.0f);
                float ih = fmaxf(__fsub_rn(rby, lty), 0.0f);
                float inter = __fmul_rn(iw, ih);
                float den = __fadd_rn(__fsub_rn(__fadd_rn(ai, areaL[j]), inter), 1e-9f);
                float iou = __fdiv_rn(inter, den);
                if (iou > NMS_THRF) bits |= (1ull << (j - j0));
            }
        }
        supL[i * 8 + w] = bits;
        if (bits) atomicOr(&nzL[i >> 6], 1ull << (i & 63));
    }
    __syncthreads();

    if (tid < 64) {
        const int lane = tid;
        unsigned long long supp = 0ull, keepm = 0ull;
        unsigned long long nzreg = (lane < 8) ? nzL[lane] : 0ull;
        #pragma unroll
        for (int t = 0; t < 8; ++t) {
            const int i0 = t * 64;
            int myi = i0 + lane;
            bool v = (myi < K_N) ? (valsL[myi] > CONF_THRF) : false;
            unsigned long long vword = __ballot(v);
            unsigned long long nzword = shfl_u64(nzreg, t);
            const int imax = (K_N - i0 < 64) ? (K_N - i0) : 64;
            for (int i2 = 0; i2 < imax; ++i2) {
                unsigned long long sw = shfl_u64(supp, t);
                bool keep_i = ((vword >> i2) & 1ull) && !((sw >> i2) & 1ull);
                if (keep_i) {
                    if (lane == t) keepm |= (1ull << i2);
                    if ((nzword >> i2) & 1ull) {
                        if (lane < 8) supp |= supL[(i0 + i2) * 8 + lane];
                    }
                }
            }
        }
        if (lane < 8) keepL[lane] = keepm;
    }
    __syncthreads();

    if (tid < K_N) {
        unsigned long long kw = keepL[tid >> 6];
        out[7 * BK + (size_t)b * K_N + tid] = (float)((kw >> (tid & 63)) & 1ull);
    }
}

extern "C" void kernel_launch(void* const* d_in, const int* in_sizes, int n_in,
                              void* d_out, int out_size, void* d_ws, size_t ws_size,
                              hipStream_t stream) {
    const float* pconf     = (const float*)d_in[0];
    const float* pcls      = (const float*)d_in[1];
    const float* ptxywh    = (const float*)d_in[2];
    const float* grid_xy   = (const float*)d_in[3];
    const float* anchor_wh = (const float*)d_in[4];
    const float* fsize     = (const float*)d_in[5];
    int total = in_sizes[0];          // B*A
    int B = total / A_N;
    if (B <= 0) return;

    float*    scores = (float*)d_ws;
    int*      labls  = (int*)((char*)d_ws + (size_t)total * 4);
    unsigned* shist  = (unsigned*)((char*)d_ws + (size_t)total * 8);
    unsigned* ustar  = shist + (size_t)B * NBUCK;
    float*    tval   = (float*)(ustar + B);
    float*    out    = (float*)d_out;

    hipLaunchKernelGGL(ustar_kernel, dim3(B), dim3(1024), 0, stream,
                       pconf, ustar, shist);
    hipLaunchKernelGGL(cand_kernel, dim3(2048), dim3(256), 0, stream,
                       pconf, pcls, scores, labls, ustar, shist, total);
    hipLaunchKernelGGL(tval_kernel, dim3(B), dim3(1024), 0, stream,
                       shist, tval);
    hipLaunchKernelGGL(rest_kernel, dim3(2048), dim3(256), 0, stream,
                       pconf, pcls, scores, labls, ustar, tval, total);
    hipLaunchKernelGGL(topk_nms_kernel, dim3(B), dim3(1024), 46592, stream,
                       scores, labls, ptxywh, grid_xy, anchor_wh, fsize, out, B);
}

// Round 14
// 159.669 us; speedup vs baseline: 1.1145x; 1.1145x over previous
//
#include <hip/hip_runtime.h>
#include <math.h>

#define A_N 10647
#define C_N 80
#define K_N 500
#define CONF_THRF 0.3f
#define NMS_THRF 0.5f

#define NBUCK 1024              // scores/ub in (0,1]: bits>>20 <= 1016
#define CAND_N 2048
#define CAND_TARGET 600         // >=600 highest-ub rows get exact scores -> t

typedef float f32x4 __attribute__((ext_vector_type(4)));

__device__ __forceinline__ float sigmoid_ref(float x) {
    float e = expf(-x);            // ocml expf, ~1ulp
    return 1.0f / (1.0f + e);      // IEEE add + IEEE div (no fast-math)
}

__device__ __forceinline__ unsigned bucket_of(float v) {
    unsigned u = __float_as_uint(v) >> 20;
    return u > 1023u ? 1023u : u;
}

__device__ __forceinline__ unsigned long long shfl_u64(unsigned long long v, int src) {
    unsigned int lo = (unsigned int)v, hi = (unsigned int)(v >> 32);
    lo = __shfl(lo, src, 64);
    hi = __shfl(hi, src, 64);
    return ((unsigned long long)hi << 32) | (unsigned long long)lo;
}

__device__ __forceinline__ unsigned long long shfl_xor_u64(unsigned long long v, int mask) {
    unsigned int lo = (unsigned int)v, hi = (unsigned int)(v >> 32);
    lo = __shfl_xor(lo, mask, 64);
    hi = __shfl_xor(hi, mask, 64);
    return ((unsigned long long)hi << 32) | (unsigned long long)lo;
}

// Exact per-row reduction over a 4-lane group (v = 5 f32x4/lane, slot sub+4j).
// Returns cls_conf (max sigmoid) + argmax label, ref-exact (see R3 notes).
__device__ __forceinline__ void reduce_core(
    const f32x4 v[5], int sub, float& sbest, int& ibest) {
    float m = -3.4e38f;
    #pragma unroll
    for (int j = 0; j < 5; ++j)
        m = fmaxf(m, fmaxf(fmaxf(v[j][0], v[j][1]), fmaxf(v[j][2], v[j][3])));
    m = fmaxf(m, __shfl_xor(m, 1, 64));
    m = fmaxf(m, __shfl_xor(m, 2, 64));

    const float win = m - 1e-4f;
    int imin = 0x7FFFFFFF, cnt = 0;
    #pragma unroll
    for (int j = 0; j < 5; ++j) {
        #pragma unroll
        for (int t = 0; t < 4; ++t) {
            int idx = (sub + 4 * j) * 4 + t;
            if (v[j][t] == m && idx < imin) imin = idx;
            cnt += (v[j][t] >= win) ? 1 : 0;
        }
    }
    {
        int o = __shfl_xor(imin, 1, 64); imin = imin < o ? imin : o;
        o = __shfl_xor(imin, 2, 64);     imin = imin < o ? imin : o;
        cnt += __shfl_xor(cnt, 1, 64);
        cnt += __shfl_xor(cnt, 2, 64);
    }

    if (cnt >= 2) {
        // rare near-tie: redo exactly as ref (max sigmoid, first occurrence)
        unsigned long long key = 0ull;
        #pragma unroll
        for (int j = 0; j < 5; ++j) {
            #pragma unroll
            for (int t = 0; t < 4; ++t) {
                float x = v[j][t];
                if (x >= win) {
                    int idx = (sub + 4 * j) * 4 + t;
                    float s = sigmoid_ref(x);
                    unsigned long long k =
                        ((unsigned long long)__float_as_uint(s) << 32) |
                        (unsigned long long)(0xFFFFu - (unsigned)idx);
                    if (k > key) key = k;
                }
            }
        }
        unsigned long long o = shfl_xor_u64(key, 1); if (o > key) key = o;
        o = shfl_xor_u64(key, 2);                    if (o > key) key = o;
        sbest = __uint_as_float((unsigned int)(key >> 32));
        ibest = 0xFFFF - (int)(key & 0xFFFFull);
    } else {
        sbest = sigmoid_ref(m);
        ibest = imin;
    }
}

// K1: per batch (1 block). ub-hist -> u* = max bucket with suffix>=600;
// compact rows with bucket(ub)>=u* into list1[b*A_N..] (dense prefix).
// Also zeroes this batch's shist slice.
__global__ __launch_bounds__(1024) void ustar_compact_kernel(
    const float* __restrict__ pconf,
    unsigned* __restrict__ shist,
    unsigned* __restrict__ ustar,
    int* __restrict__ list1,
    unsigned* __restrict__ count1) {
    __shared__ unsigned hist[NBUCK];
    __shared__ unsigned lcnt, ustarL;
    const int b = blockIdx.x, tid = threadIdx.x;
    hist[tid] = 0u;
    shist[(size_t)b * NBUCK + tid] = 0u;
    if (tid == 0) lcnt = 0u;
    __syncthreads();
    for (int i = tid; i < A_N; i += 1024) {
        float ub = sigmoid_ref(pconf[(size_t)b * A_N + i]);
        atomicAdd(&hist[bucket_of(ub)], 1u);
    }
    __syncthreads();
    for (int d = 1; d < NBUCK; d <<= 1) {
        unsigned v = (tid + d < NBUCK) ? hist[tid + d] : 0u;
        __syncthreads();
        hist[tid] += v;
        __syncthreads();
    }
    if (hist[tid] >= CAND_TARGET && (tid == NBUCK - 1 || hist[tid + 1] < CAND_TARGET))
        ustarL = (unsigned)tid;
    __syncthreads();
    const unsigned u = ustarL;
    if (tid == 0) ustar[b] = u;
    for (int i = tid; i < A_N; i += 1024) {
        int r = b * A_N + i;
        float ub = sigmoid_ref(pconf[r]);
        if (bucket_of(ub) >= u) {
            unsigned slot = atomicAdd(&lcnt, 1u);
            list1[(size_t)b * A_N + slot] = r;
        }
    }
    __syncthreads();
    if (tid == 0) count1[b] = lcnt;
}

// K2/K4: dense scoring of a compacted list. Consecutive 4-lane groups take
// consecutive list slots -> waves in the valid prefix are FULLY active
// (16 rows in flight per load instruction; no masked-gather MLP collapse).
template<bool DO_HIST>
__global__ __launch_bounds__(256) void score_list_kernel(
    const float* __restrict__ pconf,
    const float* __restrict__ pcls,
    float* __restrict__ scores,
    int* __restrict__ labels,
    const int* __restrict__ list,
    const unsigned* __restrict__ count,
    unsigned* __restrict__ shist,
    int total) {
    const int sub = threadIdx.x & 3;
    const int g0 = (blockIdx.x * 256 + threadIdx.x) >> 2;
    const int gstride = (2048 * 256) >> 2;   // 131072 groups
    for (int idx = g0; idx < total; idx += gstride) {
        int b = idx / A_N;                   // const-divisor magic mul
        int k = idx - b * A_N;
        if (k >= (int)count[b]) continue;    // contiguous prefix -> whole waves skip
        int r = list[idx];
        float ub = sigmoid_ref(pconf[r]);
        const f32x4* rp = (const f32x4*)(pcls + (size_t)r * C_N);
        f32x4 v[5];
        #pragma unroll
        for (int j = 0; j < 5; ++j) v[j] = rp[sub + 4 * j];
        float s; int ib;
        reduce_core(v, sub, s, ib);
        float sc = __fmul_rn(s, ub);         // ref: cls_conf * conf
        if (sub == 0) {
            scores[r] = sc;
            labels[r] = ib;
            if (DO_HIST)
                atomicAdd(&shist[(size_t)b * NBUCK + bucket_of(sc)], 1u);
        }
    }
}

// K3: per batch (1 block). t = lower bucket-edge where candidate-score suffix
// >= 500 (valid lower bound on the true 500th score). Compact remaining rows
// with ub >= t into list2; zero-fill scores for provably-excluded rows
// (score < ub < t <= s500, strict).
__global__ __launch_bounds__(1024) void tval_compact_kernel(
    const float* __restrict__ pconf,
    const unsigned* __restrict__ shist,
    const unsigned* __restrict__ ustar,
    float* __restrict__ scores,
    int* __restrict__ list2,
    unsigned* __restrict__ count2) {
    __shared__ unsigned hist[NBUCK];
    __shared__ unsigned lcnt;
    __shared__ float tL;
    const int b = blockIdx.x, tid = threadIdx.x;
    hist[tid] = shist[(size_t)b * NBUCK + tid];
    if (tid == 0) lcnt = 0u;
    __syncthreads();
    for (int d = 1; d < NBUCK; d <<= 1) {
        unsigned v = (tid + d < NBUCK) ? hist[tid + d] : 0u;
        __syncthreads();
        hist[tid] += v;
        __syncthreads();
    }
    if (hist[tid] >= K_N && (tid == NBUCK - 1 || hist[tid + 1] < K_N))
        tL = __uint_as_float(((unsigned)tid) << 20);
    __syncthreads();
    const float t = tL;
    const unsigned u = ustar[b];
    for (int i = tid; i < A_N; i += 1024) {
        int r = b * A_N + i;
        float ub = sigmoid_ref(pconf[r]);
        unsigned bk = bucket_of(ub);
        if (bk >= u) continue;               // already scored in K2
        if (ub >= t) {
            unsigned slot = atomicAdd(&lcnt, 1u);
            list2[(size_t)b * A_N + slot] = r;
        } else {
            scores[r] = 0.0f;                // strictly below any top-500 score
        }
    }
    __syncthreads();
    if (tid == 0) count2[b] = lcnt;
}

// K5: one block per batch. Histogram select -> 2048-key bitonic sort ->
// decode top-500 -> suppression matrix -> sequential keep-scan. (Unchanged.)
__global__ __launch_bounds__(1024) void topk_nms_kernel(
    const float* __restrict__ scores,
    const int* __restrict__ labels,
    const float* __restrict__ ptxywh,
    const float* __restrict__ grid_xy,
    const float* __restrict__ anchor_wh,
    const float* __restrict__ fsize,
    float* __restrict__ out, int B) {
    extern __shared__ unsigned char smem[];
    unsigned int* hist = (unsigned int*)smem;                     // [1024]
    unsigned long long* cand = (unsigned long long*)(smem + 4096);// [2048]
    unsigned int* cntp = (unsigned int*)(smem + 20480);
    unsigned int* Tp   = (unsigned int*)(smem + 20484);
    const int b = blockIdx.x;
    const int tid = threadIdx.x;
    const float* sb = scores + (size_t)b * A_N;

    hist[tid] = 0u;
    cand[tid] = 0ull;
    cand[tid + 1024] = 0ull;
    if (tid == 0) *cntp = 0u;
    __syncthreads();

    for (int i = tid; i < A_N; i += 1024) {
        unsigned int u = __float_as_uint(sb[i]) >> 20;
        atomicAdd(&hist[u], 1u);
    }
    __syncthreads();

    for (int d = 1; d < NBUCK; d <<= 1) {
        unsigned int v = (tid + d < NBUCK) ? hist[tid + d] : 0u;
        __syncthreads();
        hist[tid] += v;
        __syncthreads();
    }
    if (hist[tid] >= K_N && (tid == NBUCK - 1 || hist[tid + 1] < K_N)) *Tp = (unsigned)tid;
    __syncthreads();
    const unsigned int T = *Tp;
    __syncthreads();

    for (int i = tid; i < A_N; i += 1024) {
        unsigned int u = __float_as_uint(sb[i]);
        if ((u >> 20) >= T) {
            unsigned int slot = atomicAdd(cntp, 1u);
            if (slot < CAND_N)
                cand[slot] = ((unsigned long long)u << 32) |
                             (unsigned long long)(0xFFFFu - (unsigned)i);
        }
    }
    __syncthreads();

    for (int sz = 2; sz <= CAND_N; sz <<= 1) {
        for (int j = sz >> 1; j > 0; j >>= 1) {
            int i = ((tid & ~(j - 1)) << 1) | (tid & (j - 1));
            int l = i | j;
            unsigned long long a = cand[i];
            unsigned long long c = cand[l];
            bool descBlk = ((i & sz) == 0);
            if (descBlk ? (a < c) : (a > c)) { cand[i] = c; cand[l] = a; }
            __syncthreads();
        }
    }

    unsigned long long myk = 0ull;
    if (tid < K_N) myk = cand[tid];
    __syncthreads();

    float* bxL   = (float*)smem;                               // [500*4]
    float* areaL = (float*)(smem + 8000);                      // [500]
    int*   labL  = (int*)  (smem + 10000);                     // [500]
    float* valsL = (float*)(smem + 12000);                     // [500]
    unsigned long long* nzL   = (unsigned long long*)(smem + 14016); // [8]
    unsigned long long* keepL = (unsigned long long*)(smem + 14080); // [8]
    unsigned long long* supL  = (unsigned long long*)(smem + 14336); // [500*8]

    if (tid >= 512 && tid < 520) nzL[tid - 512] = 0ull;

    const size_t BK = (size_t)B * K_N;
    if (tid < K_N) {
        float scv = __uint_as_float((unsigned int)(myk >> 32));
        int idx = 0xFFFF - (int)(myk & 0xFFFFull);
        int lb = labels[(size_t)b * A_N + idx] + 1;
        const float* t4 = ptxywh + ((size_t)b * A_N + idx) * 4;
        float tx = t4[0], ty = t4[1], tw = t4[2], th = t4[3];
        float gx = grid_xy[idx * 2 + 0], gy = grid_xy[idx * 2 + 1];
        float aw = anchor_wh[idx * 2 + 0], ah = anchor_wh[idx * 2 + 1];
        float fs = fsize[idx];
        float cx = __fdiv_rn(__fadd_rn(sigmoid_ref(tx), gx), fs);
        float cy = __fdiv_rn(__fadd_rn(sigmoid_ref(ty), gy), fs);
        float wx = __fmul_rn(expf(tw), aw);
        float wy = __fmul_rn(expf(th), ah);
        float hx = __fmul_rn(0.5f, wx);
        float hy = __fmul_rn(0.5f, wy);
        float x0 = __fsub_rn(cx, hx), y0 = __fsub_rn(cy, hy);
        float x1 = __fadd_rn(cx, hx), y1 = __fadd_rn(cy, hy);
        x0 = fminf(fmaxf(x0, 0.0f), 1.0f);
        y0 = fminf(fmaxf(y0, 0.0f), 1.0f);
        x1 = fminf(fmaxf(x1, 0.0f), 1.0f);
        y1 = fminf(fmaxf(y1, 0.0f), 1.0f);
        float area = __fmul_rn(fmaxf(__fsub_rn(x1, x0), 0.0f),
                               fmaxf(__fsub_rn(y1, y0), 0.0f));
        bxL[tid * 4 + 0] = x0; bxL[tid * 4 + 1] = y0;
        bxL[tid * 4 + 2] = x1; bxL[tid * 4 + 3] = y1;
        areaL[tid] = area; labL[tid] = lb; valsL[tid] = scv;

        out[(size_t)b * K_N + tid] = (float)b;                         // ids_batch
        float* ob = out + BK + ((size_t)b * K_N + tid) * 4;            // boxes
        ob[0] = x0; ob[1] = y0; ob[2] = x1; ob[3] = y1;
        out[5 * BK + (size_t)b * K_N + tid] = (float)lb;               // labels
        out[6 * BK + (size_t)b * K_N + tid] = scv;                     // vals
    }
    __syncthreads();

    for (int task = tid; task < K_N * 8; task += 1024) {
        int i = task >> 3;
        int w = task & 7;
        float li = bxL[i * 4 + 0], ti = bxL[i * 4 + 1];
        float ri = bxL[i * 4 + 2], bi = bxL[i * 4 + 3];
        float ai = areaL[i];
        int lbi = labL[i];
        unsigned long long bits = 0ull;
        int j0 = w * 64;
        int jend = j0 + 64; if (jend > K_N) jend = K_N;
        int jst = j0 > i + 1 ? j0 : i + 1;
        for (int j = jst; j < jend; ++j) {
            if (labL[j] == lbi) {
                float lj = bxL[j * 4 + 0], tj = bxL[j * 4 + 1];
                float rj = bxL[j * 4 + 2], bj = bxL[j * 4 + 3];
                float ltx = fmaxf(li, lj), lty = fmaxf(ti, tj);
                float rbx = fminf(ri, rj), rby = fminf(bi, bj);
                float iw = fmaxf(__fsub_rn(rbx, ltx), 0.0f);
                float ih = fmaxf(__fsub_rn(rby, lty), 0.0f);
                float inter = __fmul_rn(iw, ih);
                float den = __fadd_rn(__fsub_rn(__fadd_rn(ai, areaL[j]), inter), 1e-9f);
                float iou = __fdiv_rn(inter, den);
                if (iou > NMS_THRF) bits |= (1ull << (j - j0));
            }
        }
        supL[i * 8 + w] = bits;
        if (bits) atomicOr(&nzL[i >> 6], 1ull << (i & 63));
    }
    __syncthreads();

    if (tid < 64) {
        const int lane = tid;
        unsigned long long supp = 0ull, keepm = 0ull;
        unsigned long long nzreg = (lane < 8) ? nzL[lane] : 0ull;
        #pragma unroll
        for (int t = 0; t < 8; ++t) {
            const int i0 = t * 64;
            int myi = i0 + lane;
            bool v = (myi < K_N) ? (valsL[myi] > CONF_THRF) : false;
            unsigned long long vword = __ballot(v);
            unsigned long long nzword = shfl_u64(nzreg, t);
            const int imax = (K_N - i0 < 64) ? (K_N - i0) : 64;
            for (int i2 = 0; i2 < imax; ++i2) {
                unsigned long long sw = shfl_u64(supp, t);
                bool keep_i = ((vword >> i2) & 1ull) && !((sw >> i2) & 1ull);
                if (keep_i) {
                    if (lane == t) keepm |= (1ull << i2);
                    if ((nzword >> i2) & 1ull) {
                        if (lane < 8) supp |= supL[(i0 + i2) * 8 + lane];
                    }
                }
            }
        }
        if (lane < 8) keepL[lane] = keepm;
    }
    __syncthreads();

    if (tid < K_N) {
        unsigned long long kw = keepL[tid >> 6];
        out[7 * BK + (size_t)b * K_N + tid] = (float)((kw >> (tid & 63)) & 1ull);
    }
}

extern "C" void kernel_launch(void* const* d_in, const int* in_sizes, int n_in,
                              void* d_out, int out_size, void* d_ws, size_t ws_size,
                              hipStream_t stream) {
    const float* pconf     = (const float*)d_in[0];
    const float* pcls      = (const float*)d_in[1];
    const float* ptxywh    = (const float*)d_in[2];
    const float* grid_xy   = (const float*)d_in[3];
    const float* anchor_wh = (const float*)d_in[4];
    const float* fsize     = (const float*)d_in[5];
    int total = in_sizes[0];          // B*A
    int B = total / A_N;
    if (B <= 0) return;

    char* w = (char*)d_ws;
    float*    scores = (float*)w;                      w += (size_t)total * 4;
    int*      labls  = (int*)w;                        w += (size_t)total * 4;
    int*      list1  = (int*)w;                        w += (size_t)total * 4;
    int*      list2  = (int*)w;                        w += (size_t)total * 4;
    unsigned* shist  = (unsigned*)w;                   w += (size_t)B * NBUCK * 4;
    unsigned* ustar  = (unsigned*)w;                   w += (size_t)B * 4;
    unsigned* count1 = (unsigned*)w;                   w += (size_t)B * 4;
    unsigned* count2 = (unsigned*)w;
    float*    out    = (float*)d_out;

    hipLaunchKernelGGL(ustar_compact_kernel, dim3(B), dim3(1024), 0, stream,
                       pconf, shist, ustar, list1, count1);
    hipLaunchKernelGGL((score_list_kernel<true>), dim3(2048), dim3(256), 0, stream,
                       pconf, pcls, scores, labls, list1, count1, shist, total);
    hipLaunchKernelGGL(tval_compact_kernel, dim3(B), dim3(1024), 0, stream,
                       pconf, shist, ustar, scores, list2, count2);
    hipLaunchKernelGGL((score_list_kernel<false>), dim3(2048), dim3(256), 0, stream,
                       pconf, pcls, scores, labls, list2, count2, (unsigned*)nullptr, total);
    hipLaunchKernelGGL(topk_nms_kernel, dim3(B), dim3(1024), 46592, stream,
                       scores, labls, ptxywh, grid_xy, anchor_wh, fsize, out, B);
}

// Round 15
// 143.941 us; speedup vs baseline: 1.2362x; 1.1093x over previous
//
#include <hip/hip_runtime.h>
#include <math.h>

#define A_N 10647
#define C_N 80
#define K_N 500
#define CONF_THRF 0.3f
#define NMS_THRF 0.5f

#define NBUCK 1024              // scores in (0,1): bits>>20 < 1016
#define CAND_N 2048

#define ROWS_PER_BLOCK 64
#define SC_TILES ((A_N + ROWS_PER_BLOCK - 1) / ROWS_PER_BLOCK)   // 167

typedef float f32x4 __attribute__((ext_vector_type(4)));

__device__ __forceinline__ float sigmoid_ref(float x) {
    float e = expf(-x);            // ocml expf, ~1ulp
    return 1.0f / (1.0f + e);      // IEEE add + IEEE div (no fast-math)
}

__device__ __forceinline__ unsigned long long shfl_u64(unsigned long long v, int src) {
    unsigned int lo = (unsigned int)v, hi = (unsigned int)(v >> 32);
    lo = __shfl(lo, src, 64);
    hi = __shfl(hi, src, 64);
    return ((unsigned long long)hi << 32) | (unsigned long long)lo;
}

__device__ __forceinline__ unsigned long long shfl_xor_u64(unsigned long long v, int mask) {
    unsigned int lo = (unsigned int)v, hi = (unsigned int)(v >> 32);
    lo = __shfl_xor(lo, mask, 64);
    hi = __shfl_xor(hi, mask, 64);
    return ((unsigned long long)hi << 32) | (unsigned long long)lo;
}

// Kernel A (R3 form, best measured): 4 lanes per row, no LDS. Wave = 16 rows,
// block(256) = 64 rows. Lane (sub=lane&3) reads float4 #{sub, sub+4, ...}.
__global__ __launch_bounds__(256) void score_kernel(
    const float* __restrict__ pconf,
    const float* __restrict__ pcls,
    float* __restrict__ scores,
    int* __restrict__ labels) {
    const int tid  = threadIdx.x;
    const int lane = tid & 63;
    const int wave = tid >> 6;
    const int sub  = lane & 3;
    const int b    = blockIdx.x / SC_TILES;
    const int tile = blockIdx.x % SC_TILES;
    const int row  = tile * ROWS_PER_BLOCK + wave * 16 + (lane >> 2);
    const bool valid = row < A_N;
    const size_t grow = (size_t)b * A_N + row;

    f32x4 v[5];
    if (valid) {
        const f32x4* rp = (const f32x4*)(pcls + grow * C_N);
        #pragma unroll
        for (int j = 0; j < 5; ++j) v[j] = rp[sub + 4 * j];
    } else {
        #pragma unroll
        for (int j = 0; j < 5; ++j)
            v[j] = (f32x4){-3.4e38f, -3.4e38f, -3.4e38f, -3.4e38f};
    }

    // group max (exact)
    float m = -3.4e38f;
    #pragma unroll
    for (int j = 0; j < 5; ++j)
        m = fmaxf(m, fmaxf(fmaxf(v[j][0], v[j][1]), fmaxf(v[j][2], v[j][3])));
    m = fmaxf(m, __shfl_xor(m, 1, 64));
    m = fmaxf(m, __shfl_xor(m, 2, 64));

    // first index of max + count of near-ties
    const float win = m - 1e-4f;
    int imin = 0x7FFFFFFF, cnt = 0;
    #pragma unroll
    for (int j = 0; j < 5; ++j) {
        #pragma unroll
        for (int t = 0; t < 4; ++t) {
            int idx = (sub + 4 * j) * 4 + t;
            if (v[j][t] == m && idx < imin) imin = idx;
            cnt += (v[j][t] >= win) ? 1 : 0;
        }
    }
    {
        int o = __shfl_xor(imin, 1, 64); imin = imin < o ? imin : o;
        o = __shfl_xor(imin, 2, 64);     imin = imin < o ? imin : o;
        cnt += __shfl_xor(cnt, 1, 64);
        cnt += __shfl_xor(cnt, 2, 64);
    }

    float sbest; int ibest;
    if (cnt >= 2) {
        // rare near-tie: redo exactly as ref (max sigmoid, first occurrence)
        unsigned long long key = 0ull;
        #pragma unroll
        for (int j = 0; j < 5; ++j) {
            #pragma unroll
            for (int t = 0; t < 4; ++t) {
                float x = v[j][t];
                if (x >= win) {
                    int idx = (sub + 4 * j) * 4 + t;
                    float s = sigmoid_ref(x);
                    unsigned long long k =
                        ((unsigned long long)__float_as_uint(s) << 32) |
                        (unsigned long long)(0xFFFFu - (unsigned)idx);
                    if (k > key) key = k;
                }
            }
        }
        unsigned long long o = shfl_xor_u64(key, 1); if (o > key) key = o;
        o = shfl_xor_u64(key, 2);                    if (o > key) key = o;
        sbest = __uint_as_float((unsigned int)(key >> 32));
        ibest = 0xFFFF - (int)(key & 0xFFFFull);
    } else {
        sbest = sigmoid_ref(m);
        ibest = imin;
    }

    if (sub == 0 && valid) {
        float cf = sigmoid_ref(pconf[grow]);
        scores[grow] = __fmul_rn(sbest, cf);   // ref: cls_conf * conf
        labels[grow] = ibest;
    }
}

// Kernel B: one block per batch. Histogram select -> O(n^2) RANK selection
// (replaces 66-pass bitonic: keys unique, rank = #{greater}; 2 barriers) ->
// decode top-500 -> suppression matrix -> sequential keep-scan.
__global__ __launch_bounds__(1024) void topk_nms_kernel(
    const float* __restrict__ scores,
    const int* __restrict__ labels,
    const float* __restrict__ ptxywh,
    const float* __restrict__ grid_xy,
    const float* __restrict__ anchor_wh,
    const float* __restrict__ fsize,
    float* __restrict__ out, int B) {
    extern __shared__ unsigned char smem[];
    // phase 1 layout
    unsigned int* hist = (unsigned int*)smem;                        // [1024] @0
    unsigned long long* cand   = (unsigned long long*)(smem + 4096); // [2048] @4096
    unsigned long long* sorted = (unsigned long long*)(smem + 20480);// [2048] @20480
    unsigned int* cntp = (unsigned int*)(smem + 36864);
    unsigned int* Tp   = (unsigned int*)(smem + 36868);
    const int b = blockIdx.x;
    const int tid = threadIdx.x;
    const float* sb = scores + (size_t)b * A_N;

    hist[tid] = 0u;
    cand[tid] = 0ull;
    cand[tid + 1024] = 0ull;
    if (tid == 0) *cntp = 0u;
    __syncthreads();

    // histogram of top-12 float bits (all scores positive, < 1.0)
    for (int i = tid; i < A_N; i += 1024) {
        unsigned int u = __float_as_uint(sb[i]) >> 20;
        atomicAdd(&hist[u], 1u);
    }
    __syncthreads();

    // suffix scan: hist[u] = count of items in buckets >= u
    for (int d = 1; d < NBUCK; d <<= 1) {
        unsigned int v = (tid + d < NBUCK) ? hist[tid + d] : 0u;
        __syncthreads();
        hist[tid] += v;
        __syncthreads();
    }
    if (hist[tid] >= K_N && (tid == NBUCK - 1 || hist[tid + 1] < K_N)) *Tp = (unsigned)tid;
    __syncthreads();
    const unsigned int T = *Tp;
    __syncthreads();

    // gather candidates (buckets >= T); expected ~600-800, cap CAND_N.
    // Also zero the sorted buffer (scatter target).
    sorted[tid] = 0ull;
    sorted[tid + 1024] = 0ull;
    for (int i = tid; i < A_N; i += 1024) {
        unsigned int u = __float_as_uint(sb[i]);
        if ((u >> 20) >= T) {
            unsigned int slot = atomicAdd(cntp, 1u);
            if (slot < CAND_N)
                cand[slot] = ((unsigned long long)u << 32) |
                             (unsigned long long)(0xFFFFu - (unsigned)i);
        }
    }
    __syncthreads();

    // rank selection: keys are unique (idx field) -> rank is a permutation.
    // sorted[rank] = key gives exact descending lax.top_k order.
    const int n = (*cntp < CAND_N) ? (int)*cntp : CAND_N;
    for (int i = tid; i < n; i += 1024) {
        unsigned long long k = cand[i];
        int rank = 0;
        for (int j = 0; j < n; ++j) rank += (cand[j] > k) ? 1 : 0;
        if (rank < K_N) sorted[rank] = k;
    }
    __syncthreads();

    unsigned long long myk = 0ull;
    if (tid < K_N) myk = sorted[tid];
    __syncthreads();   // smem reusable now

    // phase 2 layout (bytes)
    float* bxL   = (float*)smem;                               // [500*4]
    float* areaL = (float*)(smem + 8000);                      // [500]
    int*   labL  = (int*)  (smem + 10000);                     // [500]
    float* valsL = (float*)(smem + 12000);                     // [500]
    unsigned long long* nzL   = (unsigned long long*)(smem + 14016); // [8]
    unsigned long long* keepL = (unsigned long long*)(smem + 14080); // [8]
    unsigned long long* supL  = (unsigned long long*)(smem + 14336); // [500*8]

    if (tid >= 512 && tid < 520) nzL[tid - 512] = 0ull;

    const size_t BK = (size_t)B * K_N;
    if (tid < K_N) {
        float scv = __uint_as_float((unsigned int)(myk >> 32));
        int idx = 0xFFFF - (int)(myk & 0xFFFFull);
        int lb = labels[(size_t)b * A_N + idx] + 1;
        const float* t4 = ptxywh + ((size_t)b * A_N + idx) * 4;
        float tx = t4[0], ty = t4[1], tw = t4[2], th = t4[3];
        float gx = grid_xy[idx * 2 + 0], gy = grid_xy[idx * 2 + 1];
        float aw = anchor_wh[idx * 2 + 0], ah = anchor_wh[idx * 2 + 1];
        float fs = fsize[idx];
        float cx = __fdiv_rn(__fadd_rn(sigmoid_ref(tx), gx), fs);
        float cy = __fdiv_rn(__fadd_rn(sigmoid_ref(ty), gy), fs);
        float wx = __fmul_rn(expf(tw), aw);
        float wy = __fmul_rn(expf(th), ah);
        float hx = __fmul_rn(0.5f, wx);
        float hy = __fmul_rn(0.5f, wy);
        float x0 = __fsub_rn(cx, hx), y0 = __fsub_rn(cy, hy);
        float x1 = __fadd_rn(cx, hx), y1 = __fadd_rn(cy, hy);
        x0 = fminf(fmaxf(x0, 0.0f), 1.0f);
        y0 = fminf(fmaxf(y0, 0.0f), 1.0f);
        x1 = fminf(fmaxf(x1, 0.0f), 1.0f);
        y1 = fminf(fmaxf(y1, 0.0f), 1.0f);
        float area = __fmul_rn(fmaxf(__fsub_rn(x1, x0), 0.0f),
                               fmaxf(__fsub_rn(y1, y0), 0.0f));
        bxL[tid * 4 + 0] = x0; bxL[tid * 4 + 1] = y0;
        bxL[tid * 4 + 2] = x1; bxL[tid * 4 + 3] = y1;
        areaL[tid] = area; labL[tid] = lb; valsL[tid] = scv;

        out[(size_t)b * K_N + tid] = (float)b;                         // ids_batch
        float* ob = out + BK + ((size_t)b * K_N + tid) * 4;            // boxes
        ob[0] = x0; ob[1] = y0; ob[2] = x1; ob[3] = y1;
        out[5 * BK + (size_t)b * K_N + tid] = (float)lb;               // labels
        out[6 * BK + (size_t)b * K_N + tid] = scv;                     // vals
    }
    __syncthreads();

    // suppression matrix: sup[i][j] for j>i, 500 rows x 8 u64 words
    for (int task = tid; task < K_N * 8; task += 1024) {
        int i = task >> 3;
        int w = task & 7;
        float li = bxL[i * 4 + 0], ti = bxL[i * 4 + 1];
        float ri = bxL[i * 4 + 2], bi = bxL[i * 4 + 3];
        float ai = areaL[i];
        int lbi = labL[i];
        unsigned long long bits = 0ull;
        int j0 = w * 64;
        int jend = j0 + 64; if (jend > K_N) jend = K_N;
        int jst = j0 > i + 1 ? j0 : i + 1;
        for (int j = jst; j < jend; ++j) {
            if (labL[j] == lbi) {
                float lj = bxL[j * 4 + 0], tj = bxL[j * 4 + 1];
                float rj = bxL[j * 4 + 2], bj = bxL[j * 4 + 3];
                float ltx = fmaxf(li, lj), lty = fmaxf(ti, tj);
                float rbx = fminf(ri, rj), rby = fminf(bi, bj);
                float iw = fmaxf(__fsub_rn(rbx, ltx), 0.0f);
                float ih = fmaxf(__fsub_rn(rby, lty), 0.0f);
                float inter = __fmul_rn(iw, ih);
                float den = __fadd_rn(__fsub_rn(__fadd_rn(ai, areaL[j]), inter), 1e-9f);
                float iou = __fdiv_rn(inter, den);
                if (iou > NMS_THRF) bits |= (1ull << (j - j0));
            }
        }
        supL[i * 8 + w] = bits;
        if (bits) atomicOr(&nzL[i >> 6], 1ull << (i & 63));
    }
    __syncthreads();

    // sequential keep-scan, wave 0, register-resident suppressed bitmask
    if (tid < 64) {
        const int lane = tid;
        unsigned long long supp = 0ull, keepm = 0ull;
        unsigned long long nzreg = (lane < 8) ? nzL[lane] : 0ull;
        #pragma unroll
        for (int t = 0; t < 8; ++t) {
            const int i0 = t * 64;
            int myi = i0 + lane;
            bool v = (myi < K_N) ? (valsL[myi] > CONF_THRF) : false;
            unsigned long long vword = __ballot(v);
            unsigned long long nzword = shfl_u64(nzreg, t);
            const int imax = (K_N - i0 < 64) ? (K_N - i0) : 64;
            for (int i2 = 0; i2 < imax; ++i2) {
                unsigned long long sw = shfl_u64(supp, t);
                bool keep_i = ((vword >> i2) & 1ull) && !((sw >> i2) & 1ull);
                if (keep_i) {
                    if (lane == t) keepm |= (1ull << i2);
                    if ((nzword >> i2) & 1ull) {
                        if (lane < 8) supp |= supL[(i0 + i2) * 8 + lane];
                    }
                }
            }
        }
        if (lane < 8) keepL[lane] = keepm;
    }
    __syncthreads();

    if (tid < K_N) {
        unsigned long long kw = keepL[tid >> 6];
        out[7 * BK + (size_t)b * K_N + tid] = (float)((kw >> (tid & 63)) & 1ull);
    }
}

extern "C" void kernel_launch(void* const* d_in, const int* in_sizes, int n_in,
                              void* d_out, int out_size, void* d_ws, size_t ws_size,
                              hipStream_t stream) {
    const float* pconf     = (const float*)d_in[0];
    const float* pcls      = (const float*)d_in[1];
    const float* ptxywh    = (const float*)d_in[2];
    const float* grid_xy   = (const float*)d_in[3];
    const float* anchor_wh = (const float*)d_in[4];
    const float* fsize     = (const float*)d_in[5];
    int total = in_sizes[0];          // B*A
    int B = total / A_N;
    if (B <= 0) return;

    float* scores = (float*)d_ws;
    int*   labls  = (int*)((char*)d_ws + (size_t)total * sizeof(float));
    float* out    = (float*)d_out;

    hipLaunchKernelGGL(score_kernel, dim3(B * SC_TILES), dim3(256), 0, stream,
                       pconf, pcls, scores, labls);
    hipLaunchKernelGGL(topk_nms_kernel, dim3(B), dim3(1024), 36880, stream,
                       scores, labls, ptxywh, grid_xy, anchor_wh, fsize, out, B);
}